// Round 1
// baseline (495449.219 us; speedup 1.0000x reference)
//
#include <hip/hip_runtime.h>
#include <math.h>

// Problem constants
#define HH  1028          // hidden size
#define TT  16384         // timesteps
#define HP  1088          // padded hidden (17*64) for clean float4 strides
#define NWG 257           // workgroups per recurrence kernel (4 units each: 257*4 = 1028)

// ---------- agent-scope sync helpers ----------
__device__ __forceinline__ int ld_flag(const int* p) {
    return __hip_atomic_load(p, __ATOMIC_RELAXED, __HIP_MEMORY_SCOPE_AGENT);
}
__device__ __forceinline__ void st_flag_rel(int* p, int v) {
    // release: compiler emits s_waitcnt vmcnt(0) + buffer_wbl2 + coherent store,
    // flushing this wave's prior (normal) h-stores to the coherence point first.
    __hip_atomic_store(p, v, __ATOMIC_RELEASE, __HIP_MEMORY_SCOPE_AGENT);
}
__device__ __forceinline__ void fence_acq_agent() {
    // acquire: invalidates L1/L2 so subsequent normal loads refetch from L3 (fresh).
    __builtin_amdgcn_fence(__ATOMIC_ACQUIRE, "agent");
}

__device__ __forceinline__ float sigmf(float x) { return 1.0f / (1.0f + expf(-x)); }

// Wave-0 poll: wait until flags[0..256] all >= tgt. Called with tid<64 only.
__device__ __forceinline__ void poll_flags(const int* flags, int tgt, int tid, long long& budget) {
    const int base = tid * 4;   // lanes 0..63 cover flags[0..255]
    for (;;) {
        int f0 = ld_flag(flags + base + 0);
        int f1 = ld_flag(flags + base + 1);
        int f2 = ld_flag(flags + base + 2);
        int f3 = ld_flag(flags + base + 3);
        int f4 = (tid == 0) ? ld_flag(flags + 256) : 0x7fffffff;
        bool ok = (f0 >= tgt) & (f1 >= tgt) & (f2 >= tgt) & (f3 >= tgt) & (f4 >= tgt);
        if (__all(ok)) break;
        if (--budget < 0) break;          // hang safety valve (never hit if co-resident)
        __builtin_amdgcn_s_sleep(1);
    }
}

// ---------- init: flags = -1 ----------
__global__ void wn_init(int* fa, int* fc) {
    const int i = threadIdx.x;
    if (i < NWG) {
        __hip_atomic_store(fa + i, -1, __ATOMIC_RELAXED, __HIP_MEMORY_SCOPE_AGENT);
        __hip_atomic_store(fc + i, -1, __ATOMIC_RELAXED, __HIP_MEMORY_SCOPE_AGENT);
    }
}

// ---------- layer 0 recurrence ----------
// WG wg owns units u = wg*4 + {0..3}. 16 rows (4 gates x 4 units), 16 lanes per row.
// w_hh0 rows register-resident (68 VGPR/thread). h[t-1] broadcast via LDS.
__global__ __launch_bounds__(256, 2) void lstm0_seq(
    const float* __restrict__ x,
    const float* __restrict__ w_ih0,   // [4H] (input size 1)
    const float* __restrict__ w_hh0,   // [4H][H]
    const float* __restrict__ b_ih0,
    const float* __restrict__ b_hh0,
    float* __restrict__ h1,            // [T][H]
    int* __restrict__ flags)
{
    __shared__ float h_lds[HP];
    __shared__ float gate_lds[16];
    __shared__ float c_lds[4];

    const int tid  = threadIdx.x;
    const int wg   = blockIdx.x;        // 0..256
    const int rl   = tid >> 4;          // 0..15 : gate*4 + du
    const int k0   = tid & 15;
    const int gate = rl >> 2;
    const int du   = rl & 3;
    const int u    = wg * 4 + du;       // < 1028 always
    const int row  = gate * HH + u;

    for (int i = tid; i < HP; i += 256) h_lds[i] = 0.0f;
    if (tid < 4) c_lds[tid] = 0.0f;

    // register-resident weights: thread covers columns j = k0*4 + m*64 + q
    float wv[17][4];
#pragma unroll
    for (int m = 0; m < 17; ++m) {
        const int j = k0 * 4 + m * 64;
#pragma unroll
        for (int q = 0; q < 4; ++q)
            wv[m][q] = (j + q < HH) ? w_hh0[(size_t)row * HH + j + q] : 0.0f;
    }
    const float wx = w_ih0[row];
    const float bs = b_ih0[row] + b_hh0[row];
    __syncthreads();

    long long budget = 10000000LL;
    for (int t = 0; t < TT; ++t) {
        const float xt = x[t];
        if (t > 0) {
            if (tid < 64) poll_flags(flags, t - 1, tid, budget);
            __syncthreads();
            fence_acq_agent();
            // stage h[t-1] -> LDS (normal loads, fresh after acquire fence)
            const float* hp = h1 + (size_t)(t - 1) * HH;
            float4 v = *(const float4*)(hp + tid * 4);          // covers [0,1024)
            *(float4*)&h_lds[tid * 4] = v;
            if (tid == 0) *(float4*)&h_lds[1024] = *(const float4*)(hp + 1024);
            __syncthreads();
        }
        // partial dot: row x h over this lane's K-slice
        float acc = 0.0f;
#pragma unroll
        for (int m = 0; m < 17; ++m) {
            const float4 hv = *(const float4*)&h_lds[k0 * 4 + m * 64];
            acc = fmaf(wv[m][0], hv.x, acc);
            acc = fmaf(wv[m][1], hv.y, acc);
            acc = fmaf(wv[m][2], hv.z, acc);
            acc = fmaf(wv[m][3], hv.w, acc);
        }
#pragma unroll
        for (int off = 1; off < 16; off <<= 1) acc += __shfl_xor(acc, off);
        if (k0 == 0) gate_lds[rl] = acc + xt * wx + bs;
        __syncthreads();
        if (tid < 4) {  // tid == du: combine 4 gates of unit wg*4+tid
            const float gi = gate_lds[tid];
            const float gf = gate_lds[4 + tid];
            const float gg = gate_lds[8 + tid];
            const float go = gate_lds[12 + tid];
            const float iv = sigmf(gi), fv = sigmf(gf), gv = tanhf(gg), ov = sigmf(go);
            const float c = fv * c_lds[tid] + iv * gv;
            c_lds[tid] = c;
            h1[(size_t)t * HH + wg * 4 + tid] = ov * tanhf(c);   // normal store
        }
        if (tid == 0) st_flag_rel(flags + wg, t);                // flush + publish
    }
}

// ---------- layer 1 recurrence (fused w_ih1 GEMV, consumes finished h1) ----------
__global__ __launch_bounds__(256, 2) void lstm1_seq(
    const float* __restrict__ h1,      // [T][H] (finished, stable)
    const float* __restrict__ w_ih1,   // [4H][H]
    const float* __restrict__ w_hh1,   // [4H][H]
    const float* __restrict__ b_ih1,
    const float* __restrict__ b_hh1,
    float* __restrict__ h2,            // [T][H]
    int* __restrict__ flags)
{
    __shared__ float a_lds[HP];   // h1[t]
    __shared__ float b_lds[HP];   // h2[t-1]
    __shared__ float gate_lds[16];
    __shared__ float c_lds[4];

    const int tid  = threadIdx.x;
    const int wg   = blockIdx.x;
    const int rl   = tid >> 4;
    const int k0   = tid & 15;
    const int gate = rl >> 2;
    const int du   = rl & 3;
    const int u    = wg * 4 + du;
    const int row  = gate * HH + u;

    for (int i = tid; i < HP; i += 256) { a_lds[i] = 0.0f; b_lds[i] = 0.0f; }
    if (tid < 4) c_lds[tid] = 0.0f;

    float wiv[17][4], whv[17][4];
#pragma unroll
    for (int m = 0; m < 17; ++m) {
        const int j = k0 * 4 + m * 64;
#pragma unroll
        for (int q = 0; q < 4; ++q) {
            const bool inb = (j + q < HH);
            wiv[m][q] = inb ? w_ih1[(size_t)row * HH + j + q] : 0.0f;
            whv[m][q] = inb ? w_hh1[(size_t)row * HH + j + q] : 0.0f;
        }
    }
    const float bs = b_ih1[row] + b_hh1[row];
    __syncthreads();

    long long budget = 10000000LL;
    for (int t = 0; t < TT; ++t) {
        // prefetch h1[t] (stable data, overlap with poll)
        const float* ap = h1 + (size_t)t * HH;
        float4 av = *(const float4*)(ap + tid * 4);
        float4 av2 = make_float4(0.f, 0.f, 0.f, 0.f);
        if (tid == 0) av2 = *(const float4*)(ap + 1024);
        // prev-iter gate_lds barrier already guarantees a_lds readers are done
        *(float4*)&a_lds[tid * 4] = av;
        if (tid == 0) *(float4*)&a_lds[1024] = av2;
        if (t > 0) {
            if (tid < 64) poll_flags(flags, t - 1, tid, budget);
            __syncthreads();
            fence_acq_agent();
            const float* bp = h2 + (size_t)(t - 1) * HH;
            float4 bv = *(const float4*)(bp + tid * 4);
            *(float4*)&b_lds[tid * 4] = bv;
            if (tid == 0) *(float4*)&b_lds[1024] = *(const float4*)(bp + 1024);
        }
        __syncthreads();

        float acc = 0.0f;
#pragma unroll
        for (int m = 0; m < 17; ++m) {
            const float4 ha = *(const float4*)&a_lds[k0 * 4 + m * 64];
            const float4 hb = *(const float4*)&b_lds[k0 * 4 + m * 64];
            acc = fmaf(wiv[m][0], ha.x, acc);
            acc = fmaf(wiv[m][1], ha.y, acc);
            acc = fmaf(wiv[m][2], ha.z, acc);
            acc = fmaf(wiv[m][3], ha.w, acc);
            acc = fmaf(whv[m][0], hb.x, acc);
            acc = fmaf(whv[m][1], hb.y, acc);
            acc = fmaf(whv[m][2], hb.z, acc);
            acc = fmaf(whv[m][3], hb.w, acc);
        }
#pragma unroll
        for (int off = 1; off < 16; off <<= 1) acc += __shfl_xor(acc, off);
        if (k0 == 0) gate_lds[rl] = acc + bs;
        __syncthreads();
        if (tid < 4) {
            const float gi = gate_lds[tid];
            const float gf = gate_lds[4 + tid];
            const float gg = gate_lds[8 + tid];
            const float go = gate_lds[12 + tid];
            const float iv = sigmf(gi), fv = sigmf(gf), gv = tanhf(gg), ov = sigmf(go);
            const float c = fv * c_lds[tid] + iv * gv;
            c_lds[tid] = c;
            h2[(size_t)t * HH + wg * 4 + tid] = ov * tanhf(c);
        }
        if (tid == 0) st_flag_rel(flags + wg, t);
    }
}

// ---------- final projection: out[t] = lin_w . h2[t] + lin_b ----------
__global__ __launch_bounds__(256) void wn_proj(
    const float* __restrict__ h2,
    const float* __restrict__ lin_w,
    const float* __restrict__ lin_b,
    float* __restrict__ out)
{
    const int lane = threadIdx.x & 63;
    const int wv   = threadIdx.x >> 6;
    const int t    = blockIdx.x * 4 + wv;
    const float* hp = h2 + (size_t)t * HH;
    float acc = 0.0f;
#pragma unroll
    for (int m = 0; m < 4; ++m) {
        const int j = lane * 4 + m * 256;        // covers [0,1024)
        const float4 h4 = *(const float4*)(hp + j);
        const float4 w4 = *(const float4*)(lin_w + j);
        acc += h4.x * w4.x + h4.y * w4.y + h4.z * w4.z + h4.w * w4.w;
    }
    if (lane == 0) {
#pragma unroll
        for (int j = 1024; j < HH; ++j) acc += hp[j] * lin_w[j];
    }
#pragma unroll
    for (int off = 1; off < 64; off <<= 1) acc += __shfl_xor(acc, off);
    if (lane == 0) out[t] = acc + lin_b[0];
}

extern "C" void kernel_launch(void* const* d_in, const int* in_sizes, int n_in,
                              void* d_out, int out_size, void* d_ws, size_t ws_size,
                              hipStream_t stream) {
    const float* x     = (const float*)d_in[0];
    const float* w_ih0 = (const float*)d_in[1];
    const float* w_hh0 = (const float*)d_in[2];
    const float* b_ih0 = (const float*)d_in[3];
    const float* b_hh0 = (const float*)d_in[4];
    const float* w_ih1 = (const float*)d_in[5];
    const float* w_hh1 = (const float*)d_in[6];
    const float* b_ih1 = (const float*)d_in[7];
    const float* b_hh1 = (const float*)d_in[8];
    const float* lin_w = (const float*)d_in[9];
    const float* lin_b = (const float*)d_in[10];
    float* out = (float*)d_out;

    char* ws = (char*)d_ws;
    const size_t SZ = (size_t)TT * HH * sizeof(float);   // 67,371,008 B per h-buffer
    float* h1 = (float*)(ws);
    float* h2 = (float*)(ws + SZ);
    int* fa   = (int*)(ws + 2 * SZ);
    int* fc   = (int*)(ws + 2 * SZ + 4096);

    wn_init<<<1, 512, 0, stream>>>(fa, fc);
    lstm0_seq<<<NWG, 256, 0, stream>>>(x, w_ih0, w_hh0, b_ih0, b_hh0, h1, fa);
    lstm1_seq<<<NWG, 256, 0, stream>>>(h1, w_ih1, w_hh1, b_ih1, b_hh1, h2, fc);
    wn_proj<<<TT / 4, 256, 0, stream>>>(h2, lin_w, lin_b, out);
}

// Round 2
// 148559.473 us; speedup vs baseline: 3.3350x; 3.3350x over previous
//
#include <hip/hip_runtime.h>
#include <math.h>

// Problem constants
#define HH  1028          // hidden size
#define TT  16384         // timesteps
#define HP  1088          // padded hidden for LDS staging (17*64)
#define HS  1056          // h row stride in floats: 4224 B = 33 cache lines (row-isolated)
#define NWG 257           // workgroups per recurrence kernel (4 units each: 257*4 = 1028)

// ---------- MALL-coherent access helpers (no cache-walk maintenance ops) ----------
__device__ __forceinline__ int ld_flag(const int* p) {
    return __hip_atomic_load(p, __ATOMIC_RELAXED, __HIP_MEMORY_SCOPE_AGENT);
}
__device__ __forceinline__ void st_flag(int* p, int v) {
    __hip_atomic_store(p, v, __ATOMIC_RELAXED, __HIP_MEMORY_SCOPE_AGENT);
}
__device__ __forceinline__ void st_h(float* p, float v) {
    // relaxed agent-scope: sc1 store, performed at MALL (coherence point), no L2 allocate
    __hip_atomic_store(p, v, __ATOMIC_RELAXED, __HIP_MEMORY_SCOPE_AGENT);
}
__device__ __forceinline__ void wait_stores_flushed() {
    // h stores and flag store are issued by the same wave -> vmcnt covers them.
    asm volatile("s_waitcnt vmcnt(0)" ::: "memory");
}

__device__ __forceinline__ float sigmf(float x) { return 1.0f / (1.0f + expf(-x)); }

// Wave-0 poll: wait until flags[0..256] all >= tgt. Called with tid<64 only.
__device__ __forceinline__ void poll_flags(const int* flags, int tgt, int tid, long long& budget) {
    const int base = tid * 4;   // lanes 0..63 cover flags[0..255]
    for (;;) {
        int f0 = ld_flag(flags + base + 0);
        int f1 = ld_flag(flags + base + 1);
        int f2 = ld_flag(flags + base + 2);
        int f3 = ld_flag(flags + base + 3);
        int f4 = (tid == 0) ? ld_flag(flags + 256) : 0x7fffffff;
        bool ok = (f0 >= tgt) & (f1 >= tgt) & (f2 >= tgt) & (f3 >= tgt) & (f4 >= tgt);
        if (__all(ok)) break;
        if (--budget < 0) break;          // hang safety valve (never hit if co-resident)
        __builtin_amdgcn_s_sleep(1);
    }
    asm volatile("" ::: "memory");        // don't hoist h loads above the poll
}

// ---------- init: flags = -1 ----------
__global__ void wn_init(int* fa, int* fc) {
    const int i = threadIdx.x;
    if (i < NWG) {
        st_flag(fa + i, -1);
        st_flag(fc + i, -1);
    }
}

// ---------- layer 0 recurrence ----------
// WG wg owns units u = wg*4 + {0..3}. 16 rows (4 gates x 4 units), 16 lanes per row.
__global__ __launch_bounds__(256, 2) void lstm0_seq(
    const float* __restrict__ x,
    const float* __restrict__ w_ih0,   // [4H] (input size 1)
    const float* __restrict__ w_hh0,   // [4H][H]
    const float* __restrict__ b_ih0,
    const float* __restrict__ b_hh0,
    float* __restrict__ h1,            // [T][HS]
    int* __restrict__ flags)
{
    __shared__ float h_lds[HP];
    __shared__ float gate_lds[16];
    __shared__ float c_lds[4];

    const int tid  = threadIdx.x;
    const int wg   = blockIdx.x;        // 0..256
    const int rl   = tid >> 4;          // 0..15 : gate*4 + du
    const int k0   = tid & 15;
    const int gate = rl >> 2;
    const int du   = rl & 3;
    const int u    = wg * 4 + du;       // < 1028 always
    const int row  = gate * HH + u;

    for (int i = tid; i < HP; i += 256) h_lds[i] = 0.0f;
    if (tid < 4) c_lds[tid] = 0.0f;

    // register-resident weights: thread covers columns j = k0*4 + m*64 + q
    float wv[17][4];
#pragma unroll
    for (int m = 0; m < 17; ++m) {
        const int j = k0 * 4 + m * 64;
#pragma unroll
        for (int q = 0; q < 4; ++q)
            wv[m][q] = (j + q < HH) ? w_hh0[(size_t)row * HH + j + q] : 0.0f;
    }
    // Pin to VGPRs: opaque asm stops the compiler from rematerializing the loads
#pragma unroll
    for (int m = 0; m < 17; ++m)
#pragma unroll
        for (int q = 0; q < 4; ++q)
            asm volatile("" : "+v"(wv[m][q]));

    const float wx = w_ih0[row];
    const float bs = b_ih0[row] + b_hh0[row];
    __syncthreads();

    long long budget = 2000000000LL;
    for (int t = 0; t < TT; ++t) {
        const float xt = x[t];
        if (t > 0) {
            if (tid < 64) poll_flags(flags, t - 1, tid, budget);
            __syncthreads();
            // stage h[t-1] -> LDS; rows are cache-line isolated so these lines were
            // never fetched before all producers' write-acks reached the MALL.
            const float* hp = h1 + (size_t)(t - 1) * HS;
            float4 v = *(const float4*)(hp + tid * 4);          // covers [0,1024)
            *(float4*)&h_lds[tid * 4] = v;
            if (tid == 0) *(float4*)&h_lds[1024] = *(const float4*)(hp + 1024);
            __syncthreads();
        }
        // partial dot: row x h over this lane's K-slice
        float acc = 0.0f;
#pragma unroll
        for (int m = 0; m < 17; ++m) {
            const float4 hv = *(const float4*)&h_lds[k0 * 4 + m * 64];
            acc = fmaf(wv[m][0], hv.x, acc);
            acc = fmaf(wv[m][1], hv.y, acc);
            acc = fmaf(wv[m][2], hv.z, acc);
            acc = fmaf(wv[m][3], hv.w, acc);
        }
#pragma unroll
        for (int off = 1; off < 16; off <<= 1) acc += __shfl_xor(acc, off);
        if (k0 == 0) gate_lds[rl] = acc + xt * wx + bs;
        __syncthreads();
        if (tid < 4) {  // tid == du: combine 4 gates of unit wg*4+tid
            const float gi = gate_lds[tid];
            const float gf = gate_lds[4 + tid];
            const float gg = gate_lds[8 + tid];
            const float go = gate_lds[12 + tid];
            const float iv = sigmf(gi), fv = sigmf(gf), gv = tanhf(gg), ov = sigmf(go);
            const float c = fv * c_lds[tid] + iv * gv;
            c_lds[tid] = c;
            st_h(h1 + (size_t)t * HS + wg * 4 + tid, ov * tanhf(c));  // write-through to MALL
        }
        wait_stores_flushed();
        if (tid == 0) st_flag(flags + wg, t);
    }
}

// ---------- layer 1 recurrence (fused w_ih1 GEMV, consumes finished h1) ----------
__global__ __launch_bounds__(256, 2) void lstm1_seq(
    const float* __restrict__ h1,      // [T][HS] (finished, stable)
    const float* __restrict__ w_ih1,   // [4H][H]
    const float* __restrict__ w_hh1,   // [4H][H]
    const float* __restrict__ b_ih1,
    const float* __restrict__ b_hh1,
    float* __restrict__ h2,            // [T][HS]
    int* __restrict__ flags)
{
    __shared__ float a_lds[HP];   // h1[t]
    __shared__ float b_lds[HP];   // h2[t-1]
    __shared__ float gate_lds[16];
    __shared__ float c_lds[4];

    const int tid  = threadIdx.x;
    const int wg   = blockIdx.x;
    const int rl   = tid >> 4;
    const int k0   = tid & 15;
    const int gate = rl >> 2;
    const int du   = rl & 3;
    const int u    = wg * 4 + du;
    const int row  = gate * HH + u;

    for (int i = tid; i < HP; i += 256) { a_lds[i] = 0.0f; b_lds[i] = 0.0f; }
    if (tid < 4) c_lds[tid] = 0.0f;

    float wiv[17][4], whv[17][4];
#pragma unroll
    for (int m = 0; m < 17; ++m) {
        const int j = k0 * 4 + m * 64;
#pragma unroll
        for (int q = 0; q < 4; ++q) {
            const bool inb = (j + q < HH);
            wiv[m][q] = inb ? w_ih1[(size_t)row * HH + j + q] : 0.0f;
            whv[m][q] = inb ? w_hh1[(size_t)row * HH + j + q] : 0.0f;
        }
    }
#pragma unroll
    for (int m = 0; m < 17; ++m)
#pragma unroll
        for (int q = 0; q < 4; ++q) {
            asm volatile("" : "+v"(wiv[m][q]));
            asm volatile("" : "+v"(whv[m][q]));
        }
    const float bs = b_ih1[row] + b_hh1[row];
    __syncthreads();

    long long budget = 2000000000LL;
    for (int t = 0; t < TT; ++t) {
        // prefetch h1[t] (stable data, overlap with poll)
        const float* ap = h1 + (size_t)t * HS;
        float4 av = *(const float4*)(ap + tid * 4);
        float4 av2 = make_float4(0.f, 0.f, 0.f, 0.f);
        if (tid == 0) av2 = *(const float4*)(ap + 1024);
        // prev-iter gate_lds barrier already guarantees a_lds readers are done
        *(float4*)&a_lds[tid * 4] = av;
        if (tid == 0) *(float4*)&a_lds[1024] = av2;
        if (t > 0) {
            if (tid < 64) poll_flags(flags, t - 1, tid, budget);
            __syncthreads();
            const float* bp = h2 + (size_t)(t - 1) * HS;
            float4 bv = *(const float4*)(bp + tid * 4);
            *(float4*)&b_lds[tid * 4] = bv;
            if (tid == 0) *(float4*)&b_lds[1024] = *(const float4*)(bp + 1024);
        }
        __syncthreads();

        float acc = 0.0f;
#pragma unroll
        for (int m = 0; m < 17; ++m) {
            const float4 ha = *(const float4*)&a_lds[k0 * 4 + m * 64];
            const float4 hb = *(const float4*)&b_lds[k0 * 4 + m * 64];
            acc = fmaf(wiv[m][0], ha.x, acc);
            acc = fmaf(wiv[m][1], ha.y, acc);
            acc = fmaf(wiv[m][2], ha.z, acc);
            acc = fmaf(wiv[m][3], ha.w, acc);
            acc = fmaf(whv[m][0], hb.x, acc);
            acc = fmaf(whv[m][1], hb.y, acc);
            acc = fmaf(whv[m][2], hb.z, acc);
            acc = fmaf(whv[m][3], hb.w, acc);
        }
#pragma unroll
        for (int off = 1; off < 16; off <<= 1) acc += __shfl_xor(acc, off);
        if (k0 == 0) gate_lds[rl] = acc + bs;
        __syncthreads();
        if (tid < 4) {
            const float gi = gate_lds[tid];
            const float gf = gate_lds[4 + tid];
            const float gg = gate_lds[8 + tid];
            const float go = gate_lds[12 + tid];
            const float iv = sigmf(gi), fv = sigmf(gf), gv = tanhf(gg), ov = sigmf(go);
            const float c = fv * c_lds[tid] + iv * gv;
            c_lds[tid] = c;
            st_h(h2 + (size_t)t * HS + wg * 4 + tid, ov * tanhf(c));
        }
        wait_stores_flushed();
        if (tid == 0) st_flag(flags + wg, t);
    }
}

// ---------- final projection: out[t] = lin_w . h2[t] + lin_b ----------
__global__ __launch_bounds__(256) void wn_proj(
    const float* __restrict__ h2,
    const float* __restrict__ lin_w,
    const float* __restrict__ lin_b,
    float* __restrict__ out)
{
    const int lane = threadIdx.x & 63;
    const int wv   = threadIdx.x >> 6;
    const int t    = blockIdx.x * 4 + wv;
    const float* hp = h2 + (size_t)t * HS;
    float acc = 0.0f;
#pragma unroll
    for (int m = 0; m < 4; ++m) {
        const int j = lane * 4 + m * 256;        // covers [0,1024)
        const float4 h4 = *(const float4*)(hp + j);
        const float4 w4 = *(const float4*)(lin_w + j);
        acc += h4.x * w4.x + h4.y * w4.y + h4.z * w4.z + h4.w * w4.w;
    }
    if (lane == 0) {
#pragma unroll
        for (int j = 1024; j < HH; ++j) acc += hp[j] * lin_w[j];
    }
#pragma unroll
    for (int off = 1; off < 64; off <<= 1) acc += __shfl_xor(acc, off);
    if (lane == 0) out[t] = acc + lin_b[0];
}

extern "C" void kernel_launch(void* const* d_in, const int* in_sizes, int n_in,
                              void* d_out, int out_size, void* d_ws, size_t ws_size,
                              hipStream_t stream) {
    const float* x     = (const float*)d_in[0];
    const float* w_ih0 = (const float*)d_in[1];
    const float* w_hh0 = (const float*)d_in[2];
    const float* b_ih0 = (const float*)d_in[3];
    const float* b_hh0 = (const float*)d_in[4];
    const float* w_ih1 = (const float*)d_in[5];
    const float* w_hh1 = (const float*)d_in[6];
    const float* b_ih1 = (const float*)d_in[7];
    const float* b_hh1 = (const float*)d_in[8];
    const float* lin_w = (const float*)d_in[9];
    const float* lin_b = (const float*)d_in[10];
    float* out = (float*)d_out;

    char* ws = (char*)d_ws;
    const size_t SZ = (size_t)TT * HS * sizeof(float);   // 69,206,016 B per h-buffer
    float* h1 = (float*)(ws);
    float* h2 = (float*)(ws + SZ);
    int* fa   = (int*)(ws + 2 * SZ);
    int* fc   = (int*)(ws + 2 * SZ + 4096);

    wn_init<<<1, 512, 0, stream>>>(fa, fc);
    lstm0_seq<<<NWG, 256, 0, stream>>>(x, w_ih0, w_hh0, b_ih0, b_hh0, h1, fa);
    lstm1_seq<<<NWG, 256, 0, stream>>>(h1, w_ih1, w_hh1, b_ih1, b_hh1, h2, fc);
    wn_proj<<<TT / 4, 256, 0, stream>>>(h2, lin_w, lin_b, out);
}